// Round 1
// baseline (66.857 us; speedup 1.0000x reference)
//
#include <hip/hip_runtime.h>

#define NBITS    26
#define LO_BITS  9
#define MID_BITS 9
#define HI_BITS  8
// index j (26 bits, theta[0] = MSB): j = [hi:8][mid:9][lo:9]
// phi[j] = hiT[j>>18] * midT[(j>>9)&511] * loT[j&511]

__global__ __launch_bounds__(256) void phi_loss_kernel(
    const float* __restrict__ theta,
    const float* __restrict__ lam,
    float* __restrict__ out,
    int n4)  // number of float4 chunks = 2^24
{
    __shared__ float s[NBITS], c[NBITS];
    __shared__ __align__(16) float loT[1 << LO_BITS];
    __shared__ float midT[1 << MID_BITS];
    __shared__ float hiT[1 << HI_BITS];
    __shared__ float red[4];

    const int tid = threadIdx.x;

    if (tid < NBITS) {
        float a = fabsf(theta[tid]);
        s[tid] = sinf(a);
        c[tid] = cosf(a);
    }
    __syncthreads();

    // Build product tables. bit t of table index m maps to factor:
    //   lo:  j bit t      -> i = 25 - t
    //   mid: j bit 9 + t  -> i = 16 - t
    //   hi:  j bit 18 + t -> i = 7  - t
    for (int m = tid; m < (1 << LO_BITS); m += 256) {
        float p = 1.0f;
        #pragma unroll
        for (int t = 0; t < LO_BITS; ++t)
            p *= ((m >> t) & 1) ? c[25 - t] : s[25 - t];
        loT[m] = p;
    }
    for (int m = tid; m < (1 << MID_BITS); m += 256) {
        float p = 1.0f;
        #pragma unroll
        for (int t = 0; t < MID_BITS; ++t)
            p *= ((m >> t) & 1) ? c[16 - t] : s[16 - t];
        midT[m] = p;
    }
    for (int m = tid; m < (1 << HI_BITS); m += 256) {
        float p = 1.0f;
        #pragma unroll
        for (int t = 0; t < HI_BITS; ++t)
            p *= ((m >> t) & 1) ? c[7 - t] : s[7 - t];
        hiT[m] = p;
    }
    __syncthreads();

    const float4* __restrict__ lam4 = (const float4*)lam;
    float acc = 0.0f;
    const int stride = gridDim.x * 256;
    for (int idx = blockIdx.x * 256 + tid; idx < n4; idx += stride) {
        float4 l = lam4[idx];
        int j = idx << 2;                         // base element index (mult of 4)
        // 4 consecutive elements share hi and mid indices (lo spans 9 bits)
        float pref = hiT[j >> (LO_BITS + MID_BITS)]
                   * midT[(j >> LO_BITS) & ((1 << MID_BITS) - 1)];
        float4 lov = *(const float4*)&loT[j & ((1 << LO_BITS) - 1)];
        float d0 = fmaf(pref, lov.x, -l.x);
        float d1 = fmaf(pref, lov.y, -l.y);
        float d2 = fmaf(pref, lov.z, -l.z);
        float d3 = fmaf(pref, lov.w, -l.w);
        acc = fmaf(d0, d0, acc);
        acc = fmaf(d1, d1, acc);
        acc = fmaf(d2, d2, acc);
        acc = fmaf(d3, d3, acc);
    }

    // wave (64-lane) shuffle reduction
    #pragma unroll
    for (int off = 32; off > 0; off >>= 1)
        acc += __shfl_down(acc, off, 64);
    const int wave = tid >> 6;
    const int lane = tid & 63;
    if (lane == 0) red[wave] = acc;
    __syncthreads();
    if (tid == 0) {
        float b = (red[0] + red[1]) + (red[2] + red[3]);
        atomicAdd(out, b);
    }
}

extern "C" void kernel_launch(void* const* d_in, const int* in_sizes, int n_in,
                              void* d_out, int out_size, void* d_ws, size_t ws_size,
                              hipStream_t stream) {
    const float* theta = (const float*)d_in[0];
    const float* lam   = (const float*)d_in[1];
    float* out = (float*)d_out;

    hipMemsetAsync(out, 0, sizeof(float), stream);  // deterministic across replays

    const int n4 = in_sizes[1] >> 2;  // 2^24 float4 chunks
    phi_loss_kernel<<<2048, 256, 0, stream>>>(theta, lam, out, n4);
}

// Round 2
// 48.576 us; speedup vs baseline: 1.3764x; 1.3764x over previous
//
#include <hip/hip_runtime.h>

#define NBITS    26
#define LO_BITS  9
#define MID_BITS 9
#define HI_BITS  8
#define NBLOCKS  2048
#define NTHREADS 256
// index j (26 bits, theta[0] = MSB): j = [hi:8][mid:9][lo:9]
// phi[j] = hiT[j>>18] * midT[(j>>9)&511] * loT[j&511]
// grid-stride in float4 units: stride = 2048*256 = 2^19 float4 = 2^21 elems,
// so lo and mid indices are loop-invariant per thread; hi advances by +8.

__global__ __launch_bounds__(NTHREADS) void phi_loss_kernel(
    const float* __restrict__ theta,
    const float* __restrict__ lam,
    float* __restrict__ partial,
    int n4)
{
    __shared__ float s[NBITS], c[NBITS];
    __shared__ __align__(16) float loT[1 << LO_BITS];
    __shared__ float midT[1 << MID_BITS];
    __shared__ float hiT[1 << HI_BITS];
    __shared__ float red[4];

    const int tid = threadIdx.x;

    if (tid < NBITS) {
        float a = fabsf(theta[tid]);
        s[tid] = sinf(a);
        c[tid] = cosf(a);
    }
    __syncthreads();

    // Product tables. bit t of table index m maps to factor:
    //   lo:  j bit t      -> i = 25 - t
    //   mid: j bit 9 + t  -> i = 16 - t
    //   hi:  j bit 18 + t -> i = 7  - t
    for (int m = tid; m < (1 << LO_BITS); m += NTHREADS) {
        float p = 1.0f;
        #pragma unroll
        for (int t = 0; t < LO_BITS; ++t)
            p *= ((m >> t) & 1) ? c[25 - t] : s[25 - t];
        loT[m] = p;
    }
    for (int m = tid; m < (1 << MID_BITS); m += NTHREADS) {
        float p = 1.0f;
        #pragma unroll
        for (int t = 0; t < MID_BITS; ++t)
            p *= ((m >> t) & 1) ? c[16 - t] : s[16 - t];
        midT[m] = p;
    }
    for (int m = tid; m < (1 << HI_BITS); m += NTHREADS) {
        float p = 1.0f;
        #pragma unroll
        for (int t = 0; t < HI_BITS; ++t)
            p *= ((m >> t) & 1) ? c[7 - t] : s[7 - t];
        hiT[m] = p;
    }
    __syncthreads();

    const float4* __restrict__ lam4 = (const float4*)lam;
    const int S = NBLOCKS * NTHREADS;          // float4 stride = 2^19

    int idx = blockIdx.x * NTHREADS + tid;     // float4 index
    int j = idx << 2;                          // element index (low 2 bits 0)
    // loop-invariant prefix: mid * lo (vector of 4 consecutive lo entries)
    float mv = midT[(j >> LO_BITS) & ((1 << MID_BITS) - 1)];
    float4 lov = *(const float4*)&loT[j & ((1 << LO_BITS) - 1)];
    float4 mlv = make_float4(mv * lov.x, mv * lov.y, mv * lov.z, mv * lov.w);
    int hidx = j >> (LO_BITS + MID_BITS);      // advances by 8 per stride step

    float acc = 0.0f;
    // paired (unroll-2) iterations: two independent loads in flight
    for (; idx + S < n4; idx += 2 * S, hidx += 16) {
        float4 l0 = lam4[idx];
        float4 l1 = lam4[idx + S];
        float h0 = hiT[hidx];
        float h1 = hiT[hidx + 8];
        float d0 = fmaf(h0, mlv.x, -l0.x);
        float d1 = fmaf(h0, mlv.y, -l0.y);
        float d2 = fmaf(h0, mlv.z, -l0.z);
        float d3 = fmaf(h0, mlv.w, -l0.w);
        acc = fmaf(d0, d0, acc);
        acc = fmaf(d1, d1, acc);
        acc = fmaf(d2, d2, acc);
        acc = fmaf(d3, d3, acc);
        float e0 = fmaf(h1, mlv.x, -l1.x);
        float e1 = fmaf(h1, mlv.y, -l1.y);
        float e2 = fmaf(h1, mlv.z, -l1.z);
        float e3 = fmaf(h1, mlv.w, -l1.w);
        acc = fmaf(e0, e0, acc);
        acc = fmaf(e1, e1, acc);
        acc = fmaf(e2, e2, acc);
        acc = fmaf(e3, e3, acc);
    }
    if (idx < n4) {
        float4 l0 = lam4[idx];
        float h0 = hiT[hidx];
        float d0 = fmaf(h0, mlv.x, -l0.x);
        float d1 = fmaf(h0, mlv.y, -l0.y);
        float d2 = fmaf(h0, mlv.z, -l0.z);
        float d3 = fmaf(h0, mlv.w, -l0.w);
        acc = fmaf(d0, d0, acc);
        acc = fmaf(d1, d1, acc);
        acc = fmaf(d2, d2, acc);
        acc = fmaf(d3, d3, acc);
    }

    // wave (64-lane) shuffle reduction, then cross-wave via LDS
    #pragma unroll
    for (int off = 32; off > 0; off >>= 1)
        acc += __shfl_down(acc, off, 64);
    const int wave = tid >> 6;
    const int lane = tid & 63;
    if (lane == 0) red[wave] = acc;
    __syncthreads();
    if (tid == 0)
        partial[blockIdx.x] = (red[0] + red[1]) + (red[2] + red[3]);
}

__global__ __launch_bounds__(NTHREADS) void finish_kernel(
    const float* __restrict__ partial, float* __restrict__ out)
{
    __shared__ float red[4];
    const int tid = threadIdx.x;
    float acc = 0.0f;
    #pragma unroll
    for (int k = 0; k < NBLOCKS / NTHREADS; ++k)
        acc += partial[tid + k * NTHREADS];
    #pragma unroll
    for (int off = 32; off > 0; off >>= 1)
        acc += __shfl_down(acc, off, 64);
    if ((tid & 63) == 0) red[tid >> 6] = acc;
    __syncthreads();
    if (tid == 0)
        out[0] = (red[0] + red[1]) + (red[2] + red[3]);  // overwrite: replay-safe
}

extern "C" void kernel_launch(void* const* d_in, const int* in_sizes, int n_in,
                              void* d_out, int out_size, void* d_ws, size_t ws_size,
                              hipStream_t stream) {
    const float* theta = (const float*)d_in[0];
    const float* lam   = (const float*)d_in[1];
    float* out = (float*)d_out;
    float* partial = (float*)d_ws;   // NBLOCKS floats

    const int n4 = in_sizes[1] >> 2;  // 2^24 float4 chunks
    phi_loss_kernel<<<NBLOCKS, NTHREADS, 0, stream>>>(theta, lam, partial, n4);
    finish_kernel<<<1, NTHREADS, 0, stream>>>(partial, out);
}